// Round 20
// baseline (66.728 us; speedup 1.0000x reference)
//
#include <hip/hip_runtime.h>

// Problem constants (B,C,H,W,K) = (32,192,56,56,7)
#define BB 32
#define CC 192
#define HH 56
#define WW 56
#define KS 7
#define HW 3136        // 56*56
#define KK 49
#define CKK 9408       // C*K*K
#define PL 8
#define NCELL (BB * CC * KK)   // 301056
#define NBC (BB * CC)          // 6144
#define P0BLK 37               // pool blocks per sample
#define MIDBLK 24              // mid blocks per sample
#define TABW 56                // u32 words per channel in tap table
#define XP 2048                // u32 words per channel in x16 (32 rowpairs x 64)

typedef _Float16 h2 __attribute__((ext_vector_type(2)));   // for fdot2 only

__device__ __forceinline__ unsigned int pack16(float a, float b) {
    return __builtin_bit_cast(unsigned int, __builtin_amdgcn_cvt_pkrtz(a, b));
}

// ---------------------------------------------------------------------------
// K1: avg pool + LN0 partials + EMIT x16: rowpair-packed f16 halo-padded image.
// x16[bc][pr2][cw]: pr2 = k+2 (k = x rowpair {2k,2k+1}), cw = col+4; zeros in
// halo (pr2 0,1,30,31 and cw 0-3,60-63). Thread (c,i,j) owns an 8x8 block =
// 4 natural rowpairs x 8 cols -> 8 uint4 stores; edge threads write halo.
// ---------------------------------------------------------------------------
__global__ __launch_bounds__(256) void pool_kernel(const float* __restrict__ x,
                                                   float* __restrict__ p0,
                                                   float2* __restrict__ part0,
                                                   unsigned int* __restrict__ x16) {
    __shared__ float red[8];
    int b = blockIdx.x / P0BLK;
    int t = blockIdx.x - b * P0BLK;
    int cell = t * 256 + threadIdx.x;
    float v = 0.f;
    if (cell < CKK) {
        int c = cell / KK;
        int r = cell - c * KK;
        int i = r / KS;
        int j = r - i * KS;
        int bc = b * CC + c;
        const float* src = x + (size_t)bc * HW + (i * PL) * WW + j * PL;
        unsigned int* xp = x16 + (size_t)bc * XP;
        uint4 z = make_uint4(0u, 0u, 0u, 0u);
        float s = 0.f;
#pragma unroll
        for (int p = 0; p < 4; ++p) {
            float4 aA = *(const float4*)(src + (2 * p) * WW);
            float4 aB = *(const float4*)(src + (2 * p) * WW + 4);
            float4 bA = *(const float4*)(src + (2 * p + 1) * WW);
            float4 bB = *(const float4*)(src + (2 * p + 1) * WW + 4);
            s += aA.x + aA.y + aA.z + aA.w + aB.x + aB.y + aB.z + aB.w
               + bA.x + bA.y + bA.z + bA.w + bB.x + bB.y + bB.z + bB.w;
            int pr2 = 4 * i + p + 2;
            *(uint4*)(xp + pr2 * 64 + 4 + 8 * j) =
                make_uint4(pack16(aA.x, bA.x), pack16(aA.y, bA.y),
                           pack16(aA.z, bA.z), pack16(aA.w, bA.w));
            *(uint4*)(xp + pr2 * 64 + 8 + 8 * j) =
                make_uint4(pack16(aB.x, bB.x), pack16(aB.y, bB.y),
                           pack16(aB.z, bB.z), pack16(aB.w, bB.w));
        }
        v = s * (1.f / 64.f);
        p0[b * CKK + cell] = v;

        // ---- halo zeros ----
        if (i == 0) {
            *(uint4*)(xp + 0 * 64 + 4 + 8 * j) = z;
            *(uint4*)(xp + 0 * 64 + 8 + 8 * j) = z;
            *(uint4*)(xp + 1 * 64 + 4 + 8 * j) = z;
            *(uint4*)(xp + 1 * 64 + 8 + 8 * j) = z;
        }
        if (i == 6) {
            *(uint4*)(xp + 30 * 64 + 4 + 8 * j) = z;
            *(uint4*)(xp + 30 * 64 + 8 + 8 * j) = z;
            *(uint4*)(xp + 31 * 64 + 4 + 8 * j) = z;
            *(uint4*)(xp + 31 * 64 + 8 + 8 * j) = z;
        }
        if (j == 0) {
#pragma unroll
            for (int p = 0; p < 4; ++p) *(uint4*)(xp + (4 * i + p + 2) * 64) = z;
            if (i == 0) { *(uint4*)(xp + 0) = z;        *(uint4*)(xp + 64) = z; }
            if (i == 6) { *(uint4*)(xp + 30 * 64) = z;  *(uint4*)(xp + 31 * 64) = z; }
        }
        if (j == 6) {
#pragma unroll
            for (int p = 0; p < 4; ++p) *(uint4*)(xp + (4 * i + p + 2) * 64 + 60) = z;
            if (i == 0) { *(uint4*)(xp + 60) = z;           *(uint4*)(xp + 64 + 60) = z; }
            if (i == 6) { *(uint4*)(xp + 30 * 64 + 60) = z; *(uint4*)(xp + 31 * 64 + 60) = z; }
        }
    }
    float sv = v, sq = v * v;
#pragma unroll
    for (int o = 32; o > 0; o >>= 1) {
        sv += __shfl_down(sv, o, 64);
        sq += __shfl_down(sq, o, 64);
    }
    if ((threadIdx.x & 63) == 0) {
        red[(threadIdx.x >> 6) * 2 + 0] = sv;
        red[(threadIdx.x >> 6) * 2 + 1] = sq;
    }
    __syncthreads();
    if (threadIdx.x == 0)
        part0[blockIdx.x] = make_float2(red[0] + red[2] + red[4] + red[6],
                                        red[1] + red[3] + red[5] + red[7]);
}

// ---------------------------------------------------------------------------
// K2: LN0-normalize + depthwise 7x7 conv on the 7x7 map, one WAVE per (b,c).
// ---------------------------------------------------------------------------
__global__ __launch_bounds__(512) void mid_kernel(
    const float* __restrict__ p0,
    const float* __restrict__ ln0w, const float* __restrict__ ln0b,
    const float* __restrict__ w0,
    const float2* __restrict__ part0,
    float* __restrict__ q1,
    float2* __restrict__ part1)
{
    __shared__ float red[16];
    int tid  = threadIdx.x;
    int lane = tid & 63;
    int bc   = blockIdx.x * 8 + (tid >> 6);
    int b = bc / CC;
    int c = bc - b * CC;

    float s0 = 0.f, ss0 = 0.f;
    if (lane < P0BLK) {
        float2 p = part0[b * P0BLK + lane];
        s0 = p.x; ss0 = p.y;
    }
#pragma unroll
    for (int o = 32; o > 0; o >>= 1) {
        s0  += __shfl_down(s0, o, 64);
        ss0 += __shfl_down(ss0, o, 64);
    }
    s0  = __shfl(s0, 0, 64);
    ss0 = __shfl(ss0, 0, 64);
    float mean = s0 * (1.f / CKK);
    float rstd = rsqrtf(ss0 * (1.f / CKK) - mean * mean + 1e-5f);

    float val = 0.f;
    if (lane < KK)
        val = (p0[bc * KK + lane] - mean) * rstd * ln0w[c * KK + lane]
              + ln0b[c * KK + lane];

    int i0 = lane / KS;
    int j0 = lane - i0 * KS;
    const float* wc = w0 + c * KK;

    float acc = 0.f;
#pragma unroll
    for (int u = 0; u < KS; ++u) {
        int ii = i0 + u - 3;
#pragma unroll
        for (int v = 0; v < KS; ++v) {
            int jj = j0 + v - 3;
            bool ok = (ii >= 0) && (ii < KS) && (jj >= 0) && (jj < KS);
            int sl = ok ? (ii * KS + jj) : 0;
            float sv = __shfl(val, sl, 64);
            acc += ok ? sv * wc[u * KS + v] : 0.f;
        }
    }
    if (lane >= KK) acc = 0.f;
    if (lane < KK) q1[bc * KK + lane] = acc;

    float s2 = acc, ss2 = acc * acc;
#pragma unroll
    for (int o = 32; o > 0; o >>= 1) {
        s2  += __shfl_down(s2, o, 64);
        ss2 += __shfl_down(ss2, o, 64);
    }
    if (lane == 0) {
        red[(tid >> 6) * 2 + 0] = s2;
        red[(tid >> 6) * 2 + 1] = ss2;
    }
    __syncthreads();
    if (tid == 0) {
        float a = 0.f, q = 0.f;
#pragma unroll
        for (int w = 0; w < 8; ++w) { a += red[2 * w]; q += red[2 * w + 1]; }
        part1[blockIdx.x] = make_float2(a, q);
    }
}

// ---------------------------------------------------------------------------
// K3: tab_kernel — LN1+ReLU taps -> NATURAL-PAIRING tap tables (1 wave/bc).
//   ktab[bc][0..27]  dt[e*7+v] = h2{ e>0 ? kt[2e-1][v] : 0, kt[2e][v] }
//   ktab[bc][28..55] ct[e*7+v] = h2{ kt[2e][v], e<3 ? kt[2e+1][v] : 0 }
// (dt feeds even output rows, ct odd; pair k = x rows {2k, 2k+1}.)
// ---------------------------------------------------------------------------
__global__ __launch_bounds__(256) void tab_kernel(
    const float* __restrict__ q1, const float2* __restrict__ part1,
    const float* __restrict__ ln1w, const float* __restrict__ ln1b,
    unsigned int* __restrict__ ktab)
{
    int lane = threadIdx.x & 63;
    int bc   = blockIdx.x * 4 + (threadIdx.x >> 6);
    int b = bc / CC;
    int c = bc - b * CC;

    float s1 = 0.f, ss1 = 0.f;
    if (lane < MIDBLK) {
        float2 p = part1[b * MIDBLK + lane];
        s1 = p.x; ss1 = p.y;
    }
#pragma unroll
    for (int o = 32; o > 0; o >>= 1) {
        s1  += __shfl_down(s1, o, 64);
        ss1 += __shfl_down(ss1, o, 64);
    }
    s1  = __shfl(s1, 0, 64);
    ss1 = __shfl(ss1, 0, 64);
    float m = s1 * (1.f / CKK);
    float r = rsqrtf(ss1 * (1.f / CKK) - m * m + 1e-5f);

    float kt = 0.f;
    if (lane < KK) {
        float v = (q1[(size_t)bc * KK + lane] - m) * r * ln1w[c * KK + lane]
                  + ln1b[c * KK + lane];
        kt = v > 0.f ? v : 0.f;
    }

    bool isDt = lane < 28;
    int idx = isDt ? lane : (lane < TABW ? lane - 28 : 0);
    int e = idx / KS, v = idx - KS * e;
    int iA, iB; bool mA, mB;
    if (isDt) { mA = (e > 0); iA = mA ? (2 * e - 1) * KS + v : 0;
                mB = true;    iB = 2 * e * KS + v; }
    else      { mA = true;    iA = 2 * e * KS + v;
                mB = (e < 3); iB = mB ? (2 * e + 1) * KS + v : 0; }
    float va = __shfl(kt, iA, 64);
    float vb = __shfl(kt, iB, 64);
    unsigned int w = pack16(mA ? va : 0.f, mB ? vb : 0.f);
    if (lane < TABW)
        ktab[(size_t)bc * TABW + lane] = w;
}

// ---------------------------------------------------------------------------
// K4: per-(b,c) depthwise 7x7 SAME conv — NO LDS, NO BARRIER.
// Reads the pre-packed x16 directly (L3/L1-resident); lane owns output col
// `lane`; per step s (pr2 = wid*7+s, s=0..10): 7 coalesced u32 loads feed
// dot2s: accL[s-e] += dot2(w, dt[e]), accH[s-1-e] += dot2(w, ct[e]).
// 392 dot2/wave; ping-pong prefetch hides load latency.
// ---------------------------------------------------------------------------
__global__ __launch_bounds__(256) void conv_kernel(
    const unsigned int* __restrict__ x16,
    const unsigned int* __restrict__ ktab,
    float* __restrict__ out)
{
    int bc   = blockIdx.x;
    int tid  = threadIdx.x;
    int lane = tid & 63;
    int wid  = tid >> 6;

    // ---- tap tables (block-uniform -> s_load / SGPRs) ----
    const uint4* tb = (const uint4*)(ktab + (size_t)bc * TABW);
    unsigned int dt[28], ct[28];
#pragma unroll
    for (int i = 0; i < 7; ++i) {
        uint4 t4 = tb[i];
        dt[4 * i + 0] = t4.x; dt[4 * i + 1] = t4.y;
        dt[4 * i + 2] = t4.z; dt[4 * i + 3] = t4.w;
    }
#pragma unroll
    for (int i = 0; i < 7; ++i) {
        uint4 t4 = tb[7 + i];
        ct[4 * i + 0] = t4.x; ct[4 * i + 1] = t4.y;
        ct[4 * i + 2] = t4.z; ct[4 * i + 3] = t4.w;
    }

    int ll = lane < 56 ? lane : 55;      // clamp: lanes 56-63 duplicate lane 55
    const unsigned int* base = x16 + (size_t)bc * XP + (wid * 7) * 64 + ll + 1;

    float accL[7], accH[7];
#pragma unroll
    for (int t = 0; t < 7; ++t) { accL[t] = 0.f; accH[t] = 0.f; }

    unsigned int wa[KS], wb[KS];
#pragma unroll
    for (int j = 0; j < KS; ++j) wa[j] = base[j];          // step s=0

#define H2(u) __builtin_bit_cast(h2, (u))
#define CONV_STEP(S, CUR)                                                     \
    {                                                                         \
        _Pragma("unroll")                                                     \
        for (int e = 0; e < 4; ++e) {                                         \
            int tl = (S) - e;                                                 \
            if (tl >= 0 && tl <= 6) {                                         \
                _Pragma("unroll")                                             \
                for (int vv = 0; vv < KS; ++vv)                               \
                    accL[tl] = __builtin_amdgcn_fdot2(H2(CUR[vv]),            \
                                   H2(dt[e * KS + vv]), accL[tl], false);     \
            }                                                                 \
            int th = (S) - 1 - e;                                             \
            if (th >= 0 && th <= 6) {                                         \
                _Pragma("unroll")                                             \
                for (int vv = 0; vv < KS; ++vv)                               \
                    accH[th] = __builtin_amdgcn_fdot2(H2(CUR[vv]),            \
                                   H2(ct[e * KS + vv]), accH[th], false);     \
            }                                                                 \
        }                                                                     \
    }

#pragma unroll
    for (int ss = 0; ss < 5; ++ss) {
        int s0 = 2 * ss, s1 = 2 * ss + 1;
        {
            const unsigned int* np = base + s1 * 64;
#pragma unroll
            for (int j = 0; j < KS; ++j) wb[j] = np[j];
        }
        CONV_STEP(s0, wa);
        {
            const unsigned int* np = base + (s0 + 2) * 64;
#pragma unroll
            for (int j = 0; j < KS; ++j) wa[j] = np[j];
        }
        CONV_STEP(s1, wb);
    }
    CONV_STEP(10, wa);
#undef CONV_STEP
#undef H2

    if (lane < WW) {
        float* ob = out + (size_t)bc * HW + (wid * 14) * WW + lane;
#pragma unroll
        for (int t = 0; t < 7; ++t) {
            ob[(2 * t) * WW]     = accL[t];
            ob[(2 * t + 1) * WW] = accH[t];
        }
    }
}

// ---------------------------------------------------------------------------
extern "C" void kernel_launch(void* const* d_in, const int* in_sizes, int n_in,
                              void* d_out, int out_size, void* d_ws, size_t ws_size,
                              hipStream_t stream) {
    const float* x    = (const float*)d_in[0];
    const float* ln0w = (const float*)d_in[1];
    const float* ln0b = (const float*)d_in[2];
    const float* w0   = (const float*)d_in[3];
    const float* ln1w = (const float*)d_in[4];
    const float* ln1b = (const float*)d_in[5];
    float* out = (float*)d_out;

    float*  p0    = (float*)d_ws;                     // [NCELL]
    float*  q1    = p0 + NCELL;                       // [NCELL]
    float2* part0 = (float2*)(q1 + NCELL);            // [BB*P0BLK]
    float2* part1 = part0 + BB * P0BLK;               // [BB*MIDBLK]
    unsigned int* ktab = (unsigned int*)(part1 + BB * MIDBLK);   // [NBC*TABW]
    unsigned int* x16  = ktab + (size_t)NBC * TABW;   // [NBC*XP] = 48 MB

    pool_kernel<<<BB * P0BLK, 256, 0, stream>>>(x, p0, part0, x16);
    mid_kernel <<<BB * MIDBLK, 512, 0, stream>>>(p0, ln0w, ln0b, w0, part0, q1, part1);
    tab_kernel <<<NBC / 4, 256, 0, stream>>>(q1, part1, ln1w, ln1b, ktab);
    conv_kernel<<<NBC, 256, 0, stream>>>(x16, ktab, out);
}